// Round 11
// baseline (111.395 us; speedup 1.0000x reference)
//
#include <hip/hip_runtime.h>
#include <hip/hip_cooperative_groups.h>
#include <math.h>

namespace cg = cooperative_groups;

#define W128  128
#define NNODE 1024
#define NREL  12
#define TS    72        // bf16 LDS tile stride (144B rows)

// ws layout (float offsets)
#define OFF_ARG1  0         // 128x1024 f32
#define OFF_ARG2  131072    // 128x1024 f32
#define OFF_ARG2B 262144    // 128x1024 bf16 (65536 floats)
#define OFF_PART  327680    // partF 16x1024x128 bf16, then partB same

typedef short bf16x8 __attribute__((ext_vector_type(8)));
typedef float f32x4  __attribute__((ext_vector_type(4)));

__device__ __forceinline__ short bf16t(float x) {
    return (short)(__float_as_uint(x) >> 16);
}
__device__ __forceinline__ float bf16f(short s) {
    return __uint_as_float((unsigned)(unsigned short)s << 16);
}
__device__ __forceinline__ unsigned pk2(float lo, float hi) {
    return (__float_as_uint(hi) & 0xFFFF0000u) | (__float_as_uint(lo) >> 16);
}

// One cooperative kernel, 256 blocks x 512 threads (1 block/CU), 3 phases.
__global__ __launch_bounds__(512) void k_fused(
        const float* __restrict__ inputs, const float* __restrict__ db,
        const float* __restrict__ a1w,    const float* __restrict__ a2w,
        const float* __restrict__ opww,   const float* __restrict__ chw,
        float* __restrict__ ws, short* __restrict__ x2b,
        short* __restrict__ partF, short* __restrict__ partB,
        float* __restrict__ out) {
    // phase-aliased LDS: args needs 33280 B (lin 16896 + sm1/sm2 16384);
    // chain needs 30720 B (Tf 9216 + Tt 9216 + wfs 6144 + wbs 6144)
    __shared__ __align__(16) char smem[33536];
    cg::grid_group grid = cg::this_grid();
    int t   = threadIdx.x;
    int bid = blockIdx.x;

    // ============ phase 1: arg1/arg2 (+ in-block column softmaxes) ==========
    {
        float* lin = (float*)smem;               // [128][33]
        float* sm1 = (float*)(smem + 16896);     // [16][128]
        float* sm2 = sm1 + 16 * W128;            // [16][128]
        int n0 = (bid & 31) * 32;
        int w0 = (bid >> 5) * 16;
        // stage inputs[128][32] once
#pragma unroll
        for (int u = 0; u < 8; ++u) {
            int idx = t + u * 512;
            int j = idx >> 5, nn = idx & 31;
            lin[j * 33 + nn] = inputs[j * NNODE + n0 + nn];
        }
        // 32 column softmaxes (16 w x {a1w,a2w}), 16 lanes per column
        {
            int c = t >> 4, i = t & 15;
            const float* src = (c < 16) ? a1w : a2w;
            float* dst = (c < 16) ? sm1 : sm2;
            int w_loc = c & 15;
            int wcol = w0 + w_loc;
            float v[8]; float mx = -1e30f;
#pragma unroll
            for (int k = 0; k < 8; ++k) {
                v[k] = src[(i * 8 + k) * W128 + wcol];
                mx = fmaxf(mx, v[k]);
            }
#pragma unroll
            for (int off = 8; off; off >>= 1) mx = fmaxf(mx, __shfl_xor(mx, off));
            float s = 0.f;
#pragma unroll
            for (int k = 0; k < 8; ++k) { v[k] = expf(v[k] - mx); s += v[k]; }
#pragma unroll
            for (int off = 8; off; off >>= 1) s += __shfl_xor(s, off);
            float inv = 1.0f / s;
#pragma unroll
            for (int k = 0; k < 8; ++k) dst[w_loc * W128 + i * 8 + k] = v[k] * inv;
        }
        __syncthreads();
        // each thread: one (n, w) pair
        int nn = t & 31, w_loc = t >> 5;
        int n = n0 + nn, w = w0 + w_loc;
        const float* s1 = sm1 + w_loc * W128;
        const float* s2 = sm2 + w_loc * W128;
        float a1 = 0.f, a2 = 0.f;
#pragma unroll 4
        for (int j = 0; j < W128; ++j) {
            float in = lin[j * 33 + nn];
            a1 = fmaf(s1[j], in, a1);
            a2 = fmaf(s2[j], in, a2);
        }
        ws[OFF_ARG1 + w * NNODE + n] = a1;
        ws[OFF_ARG2 + w * NNODE + n] = a2;
        x2b[w * NNODE + n] = bf16t(a2);
    }

    // prefetch first db tile (in flight across the grid sync)
    int bx = bid & 15, by = bid >> 4;
    int B0 = bx * 64, A0 = by * 64;
    int a0 = 2 * (t >> 4), c0 = 4 * (t & 15);
    const float* gbase = db + (size_t)(A0 + a0) * NNODE + B0 + c0;
    const size_t rstep = (size_t)NNODE * NNODE;
    float4 g0 = *(const float4*)(gbase);
    float4 g1 = *(const float4*)(gbase + NNODE);

    grid.sync();

    // ============ phase 2: chain (dual-use 64x64 tile, MFMA) ================
    {
        short* Tf  = (short*)smem;                   // [64][TS] T[a][b]
        short* Tt  = Tf + 64 * TS;                   // [64][TS] T^T[c][a]
        float* wfs = (float*)(smem + 18432);         // [128][12]
        float* wbs = wfs + 128 * NREL;               // [128][12]

        // in-block chain-weight softmax (replaces k_prep's wf/wb)
        if (t < 128) {
            float u[24]; float mx = -1e30f;
            for (int k = 0; k < 24; ++k) { u[k] = chw[t * 24 + k]; mx = fmaxf(mx, u[k]); }
            float s = 0.f;
            for (int k = 0; k < 24; ++k) { u[k] = expf(u[k] - mx); s += u[k]; }
            float inv = 1.0f / s;
            for (int k = 0; k < 12; ++k) wfs[t * NREL + k] = u[k] * inv;
            for (int k = 0; k < 12; ++k) wbs[t * NREL + k] = u[12 + k] * inv;
        }

        int l   = t & 63, wid = t >> 6;
        int wm  = wid >> 2;          // 0..1 : node-half (m)
        int wn  = wid & 3;           // 0..3 : w-quarter (n)
        int l16 = l & 15, lq = l >> 4;

        // loop-invariant B-frags from x2b
        bf16x8 bfF[2][2], bfB[2][2];
#pragma unroll
        for (int ni = 0; ni < 2; ++ni)
#pragma unroll
            for (int ks = 0; ks < 2; ++ks) {
                int w = wn * 32 + ni * 16 + l16;
                bfF[ni][ks] = *(const bf16x8*)&x2b[w * NNODE + A0 + ks * 32 + lq * 8];
                bfB[ni][ks] = *(const bf16x8*)&x2b[w * NNODE + B0 + ks * 32 + lq * 8];
            }

        f32x4 accF[2][2], accB[2][2];
#pragma unroll
        for (int mi = 0; mi < 2; ++mi)
#pragma unroll
            for (int ni = 0; ni < 2; ++ni) {
                accF[mi][ni] = (f32x4){0.f, 0.f, 0.f, 0.f};
                accB[mi][ni] = (f32x4){0.f, 0.f, 0.f, 0.f};
            }

#pragma unroll 2
        for (int r = 0; r < NREL; ++r) {
            // stage packed bf16 tiles (pack once; consumers read b128 only)
            uint2 p0 = {pk2(g0.x, g0.y), pk2(g0.z, g0.w)};
            uint2 p1 = {pk2(g1.x, g1.y), pk2(g1.z, g1.w)};
            *(uint2*)&Tf[a0 * TS + c0]       = p0;
            *(uint2*)&Tf[(a0 + 1) * TS + c0] = p1;
            *(unsigned*)&Tt[(c0 + 0) * TS + a0] = pk2(g0.x, g1.x);
            *(unsigned*)&Tt[(c0 + 1) * TS + a0] = pk2(g0.y, g1.y);
            *(unsigned*)&Tt[(c0 + 2) * TS + a0] = pk2(g0.z, g1.z);
            *(unsigned*)&Tt[(c0 + 3) * TS + a0] = pk2(g0.w, g1.w);
            __syncthreads();

            float4 n0v = g0, n1v = g1;
            if (r + 1 < NREL) {
                const float* g = gbase + (size_t)(r + 1) * rstep;
                n0v = *(const float4*)(g);
                n1v = *(const float4*)(g + NNODE);
            }

            f32x4 tF[2][2], tB[2][2];
#pragma unroll
            for (int mi = 0; mi < 2; ++mi)
#pragma unroll
                for (int ni = 0; ni < 2; ++ni) {
                    tF[mi][ni] = (f32x4){0.f, 0.f, 0.f, 0.f};
                    tB[mi][ni] = (f32x4){0.f, 0.f, 0.f, 0.f};
                }

#pragma unroll
            for (int ks = 0; ks < 2; ++ks) {
                bf16x8 AF[2], AB[2];
#pragma unroll
                for (int mi = 0; mi < 2; ++mi) {
                    int row = wm * 32 + mi * 16 + l16;
                    int off = ks * 32 + lq * 8;
                    AF[mi] = *(const bf16x8*)&Tt[row * TS + off];
                    AB[mi] = *(const bf16x8*)&Tf[row * TS + off];
                }
#pragma unroll
                for (int mi = 0; mi < 2; ++mi)
#pragma unroll
                    for (int ni = 0; ni < 2; ++ni) {
                        tF[mi][ni] = __builtin_amdgcn_mfma_f32_16x16x32_bf16(
                            AF[mi], bfF[ni][ks], tF[mi][ni], 0, 0, 0);
                        tB[mi][ni] = __builtin_amdgcn_mfma_f32_16x16x32_bf16(
                            AB[mi], bfB[ni][ks], tB[mi][ni], 0, 0, 0);
                    }
            }
            __syncthreads();

            // fold per-(w,r) chain weights (w = lane column)
#pragma unroll
            for (int ni = 0; ni < 2; ++ni) {
                int w = wn * 32 + ni * 16 + l16;
                float wfv = wfs[w * NREL + r];
                float wbv = wbs[w * NREL + r];
#pragma unroll
                for (int mi = 0; mi < 2; ++mi)
#pragma unroll
                    for (int v = 0; v < 4; ++v) {
                        accF[mi][ni][v] += wfv * tF[mi][ni][v];
                        accB[mi][ni][v] += wbv * tB[mi][ni][v];
                    }
            }
            g0 = n0v; g1 = n1v;
        }

        // bf16 partials, [node][w]-major
#pragma unroll
        for (int mi = 0; mi < 2; ++mi)
#pragma unroll
            for (int v = 0; v < 4; ++v) {
                int m = wm * 32 + mi * 16 + lq * 4 + v;
#pragma unroll
                for (int ni = 0; ni < 2; ++ni) {
                    int w = wn * 32 + ni * 16 + l16;
                    partF[(size_t)by * (NNODE * W128) + (B0 + m) * W128 + w]
                        = bf16t(accF[mi][ni][v]);
                    partB[(size_t)bx * (NNODE * W128) + (A0 + m) * W128 + w]
                        = bf16t(accB[mi][ni][v]);
                }
            }
    }

    grid.sync();

    // ============ phase 3: reduce + op combine (1 elem/thread) ==============
    {
        int w = t & 127;                 // lane-fast -> coalesced partial reads
        int n = (bid << 2) + (t >> 7);   // 4 nodes per block
        size_t base = (size_t)n * W128 + w;
        float ch = 0.f;
#pragma unroll
        for (int s = 0; s < 16; ++s) {
            ch += bf16f(partF[(size_t)s * (NNODE * W128) + base])
                + bf16f(partB[(size_t)s * (NNODE * W128) + base]);
        }
        // in-thread op-weight softmax (replaces k_prep's opw)
        float v[5], mx = -1e30f;
#pragma unroll
        for (int k = 0; k < 5; ++k) { v[k] = opww[w * 5 + k]; mx = fmaxf(mx, v[k]); }
        float s5 = 0.f;
#pragma unroll
        for (int k = 0; k < 5; ++k) { v[k] = expf(v[k] - mx); s5 += v[k]; }
        float inv = 1.0f / s5;
        float a1 = ws[OFF_ARG1 + w * NNODE + n];
        float a2 = ws[OFF_ARG2 + w * NNODE + n];
        float p = a1 * a2;
        out[w * NNODE + n] = inv * (v[0] * a2 + v[1] * p + v[2] * (a1 + a2 - p)
                           + v[3] * (1.0f - expf(-ch)) + v[4] * (1.0f - a1));
    }
}

extern "C" void kernel_launch(void* const* d_in, const int* in_sizes, int n_in,
                              void* d_out, int out_size, void* d_ws, size_t ws_size,
                              hipStream_t stream) {
    const float* inputs = (const float*)d_in[0];
    const float* db     = (const float*)d_in[1];
    const float* a1w    = (const float*)d_in[2];
    const float* a2w    = (const float*)d_in[3];
    const float* opww   = (const float*)d_in[4];
    const float* chw    = (const float*)d_in[5];
    float* ws  = (float*)d_ws;
    float* out = (float*)d_out;
    short* x2b   = (short*)(ws + OFF_ARG2B);
    short* partF = (short*)(ws + OFF_PART);
    short* partB = partF + (size_t)16 * NNODE * W128;

    void* kargs[] = {(void*)&inputs, (void*)&db, (void*)&a1w, (void*)&a2w,
                     (void*)&opww, (void*)&chw, (void*)&ws, (void*)&x2b,
                     (void*)&partF, (void*)&partB, (void*)&out};
    hipLaunchCooperativeKernel((const void*)k_fused, dim3(256), dim3(512),
                               kargs, 0, stream);
}

// Round 13
// 33.944 us; speedup vs baseline: 3.2817x; 3.2817x over previous
//
#include <hip/hip_runtime.h>
#include <math.h>

#define W128  128
#define NNODE 1024
#define NREL  12
#define TS    72        // bf16 LDS tile stride (144B rows)

// ws layout (float offsets)
#define OFF_ARG1  0         // 128x1024 f32
#define OFF_ARG2  131072    // 128x1024 f32
#define OFF_ARG2B 262144    // 128x1024 bf16 (65536 floats)
#define OFF_PART  327680    // partF 16x1024x128 bf16, then partB same

typedef short bf16x8 __attribute__((ext_vector_type(8)));
typedef short short4v __attribute__((ext_vector_type(4)));
typedef float f32x4  __attribute__((ext_vector_type(4)));

__device__ __forceinline__ short bf16t(float x) {
    return (short)(__float_as_uint(x) >> 16);
}
__device__ __forceinline__ float bf16f(short s) {
    return __uint_as_float((unsigned)(unsigned short)s << 16);
}
__device__ __forceinline__ unsigned pk2(float lo, float hi) {
    return (__float_as_uint(hi) & 0xFFFF0000u) | (__float_as_uint(lo) >> 16);
}

// ---------------- args (+ in-block column softmaxes; replaces k_prep a1/a2) --
// grid 256: block = 32 n x 16 w tile, 512 threads. Verified as fused phase 1.
__global__ __launch_bounds__(512) void k_args3(const float* __restrict__ inputs,
                                               const float* __restrict__ a1w,
                                               const float* __restrict__ a2w,
                                               float* __restrict__ ws,
                                               short* __restrict__ x2b) {
    __shared__ __align__(16) char smem[33280];
    float* lin = (float*)smem;               // [128][33]
    float* sm1 = (float*)(smem + 16896);     // [16][128]
    float* sm2 = sm1 + 16 * W128;            // [16][128]
    int t = threadIdx.x;
    int bid = blockIdx.x;
    int n0 = (bid & 31) * 32;
    int w0 = (bid >> 5) * 16;
    // stage inputs[128][32] once
#pragma unroll
    for (int u = 0; u < 8; ++u) {
        int idx = t + u * 512;
        int j = idx >> 5, nn = idx & 31;
        lin[j * 33 + nn] = inputs[j * NNODE + n0 + nn];
    }
    // 32 column softmaxes (16 w x {a1w,a2w}), 16 lanes per column
    {
        int c = t >> 4, i = t & 15;
        const float* src = (c < 16) ? a1w : a2w;
        float* dst = (c < 16) ? sm1 : sm2;
        int w_loc = c & 15;
        int wcol = w0 + w_loc;
        float v[8]; float mx = -1e30f;
#pragma unroll
        for (int k = 0; k < 8; ++k) {
            v[k] = src[(i * 8 + k) * W128 + wcol];
            mx = fmaxf(mx, v[k]);
        }
#pragma unroll
        for (int off = 8; off; off >>= 1) mx = fmaxf(mx, __shfl_xor(mx, off));
        float s = 0.f;
#pragma unroll
        for (int k = 0; k < 8; ++k) { v[k] = expf(v[k] - mx); s += v[k]; }
#pragma unroll
        for (int off = 8; off; off >>= 1) s += __shfl_xor(s, off);
        float inv = 1.0f / s;
#pragma unroll
        for (int k = 0; k < 8; ++k) dst[w_loc * W128 + i * 8 + k] = v[k] * inv;
    }
    __syncthreads();
    // each thread: one (n, w) pair
    int nn = t & 31, w_loc = t >> 5;
    int n = n0 + nn, w = w0 + w_loc;
    const float* s1 = sm1 + w_loc * W128;
    const float* s2 = sm2 + w_loc * W128;
    float a1 = 0.f, a2 = 0.f;
#pragma unroll 4
    for (int j = 0; j < W128; ++j) {
        float in = lin[j * 33 + nn];
        a1 = fmaf(s1[j], in, a1);
        a2 = fmaf(s2[j], in, a2);
    }
    ws[OFF_ARG1 + w * NNODE + n] = a1;
    ws[OFF_ARG2 + w * NNODE + n] = a2;
    x2b[w * NNODE + n] = bf16t(a2);
}

// ---------------- chain (+ in-block wf/wb softmax; replaces k_prep wf/wb) ----
// Round-10 k_chain3 structure, verified. grid (16,16), 512 threads.
__global__ __launch_bounds__(512) void k_chain4(const float* __restrict__ db,
                                                const float* __restrict__ chw,
                                                const short* __restrict__ x2b,
                                                short* __restrict__ partF,
                                                short* __restrict__ partB) {
    __shared__ __align__(16) short Tf[64 * TS];  // T[a][b]
    __shared__ __align__(16) short Tt[64 * TS];  // T^T[c][a]
    __shared__ float wfs[W128 * NREL];
    __shared__ float wbs[W128 * NREL];

    int tid = threadIdx.x;
    int B0  = blockIdx.x * 64;   // fwd out-node range / bwd contraction range
    int A0  = blockIdx.y * 64;   // bwd out-node range / fwd contraction range

    // issue first tile's global loads ASAP (overlap with softmax below)
    int a0 = 2 * (tid >> 4), c0 = 4 * (tid & 15);
    const float* gbase = db + (size_t)(A0 + a0) * NNODE + B0 + c0;
    const size_t rstep = (size_t)NNODE * NNODE;
    float4 g0 = *(const float4*)(gbase);
    float4 g1 = *(const float4*)(gbase + NNODE);

    // in-block chain-weight softmax (verified in fused phase 2)
    if (tid < 128) {
        float u[24]; float mx = -1e30f;
        for (int k = 0; k < 24; ++k) { u[k] = chw[tid * 24 + k]; mx = fmaxf(mx, u[k]); }
        float s = 0.f;
        for (int k = 0; k < 24; ++k) { u[k] = expf(u[k] - mx); s += u[k]; }
        float inv = 1.0f / s;
        for (int k = 0; k < 12; ++k) wfs[tid * NREL + k] = u[k] * inv;
        for (int k = 0; k < 12; ++k) wbs[tid * NREL + k] = u[12 + k] * inv;
    }

    int l   = tid & 63, wid = tid >> 6;
    int wm  = wid >> 2;          // 0..1 : node-half (m)
    int wn  = wid & 3;           // 0..3 : w-quarter (n)
    int l16 = l & 15, lq = l >> 4;

    // loop-invariant B-frags from x2b
    bf16x8 bfF[2][2], bfB[2][2];
#pragma unroll
    for (int ni = 0; ni < 2; ++ni)
#pragma unroll
        for (int ks = 0; ks < 2; ++ks) {
            int w = wn * 32 + ni * 16 + l16;
            bfF[ni][ks] = *(const bf16x8*)&x2b[w * NNODE + A0 + ks * 32 + lq * 8];
            bfB[ni][ks] = *(const bf16x8*)&x2b[w * NNODE + B0 + ks * 32 + lq * 8];
        }

    f32x4 accF[2][2], accB[2][2];
#pragma unroll
    for (int mi = 0; mi < 2; ++mi)
#pragma unroll
        for (int ni = 0; ni < 2; ++ni) {
            accF[mi][ni] = (f32x4){0.f, 0.f, 0.f, 0.f};
            accB[mi][ni] = (f32x4){0.f, 0.f, 0.f, 0.f};
        }

#pragma unroll 2
    for (int r = 0; r < NREL; ++r) {
        // stage packed bf16 tiles (pack once; consumers read b128 only)
        uint2 p0 = {pk2(g0.x, g0.y), pk2(g0.z, g0.w)};
        uint2 p1 = {pk2(g1.x, g1.y), pk2(g1.z, g1.w)};
        *(uint2*)&Tf[a0 * TS + c0]       = p0;
        *(uint2*)&Tf[(a0 + 1) * TS + c0] = p1;
        *(unsigned*)&Tt[(c0 + 0) * TS + a0] = pk2(g0.x, g1.x);
        *(unsigned*)&Tt[(c0 + 1) * TS + a0] = pk2(g0.y, g1.y);
        *(unsigned*)&Tt[(c0 + 2) * TS + a0] = pk2(g0.z, g1.z);
        *(unsigned*)&Tt[(c0 + 3) * TS + a0] = pk2(g0.w, g1.w);
        __syncthreads();

        float4 n0v = g0, n1v = g1;
        if (r + 1 < NREL) {
            const float* g = gbase + (size_t)(r + 1) * rstep;
            n0v = *(const float4*)(g);
            n1v = *(const float4*)(g + NNODE);
        }

        f32x4 tF[2][2], tB[2][2];
#pragma unroll
        for (int mi = 0; mi < 2; ++mi)
#pragma unroll
            for (int ni = 0; ni < 2; ++ni) {
                tF[mi][ni] = (f32x4){0.f, 0.f, 0.f, 0.f};
                tB[mi][ni] = (f32x4){0.f, 0.f, 0.f, 0.f};
            }

#pragma unroll
        for (int ks = 0; ks < 2; ++ks) {
            bf16x8 AF[2], AB[2];
#pragma unroll
            for (int mi = 0; mi < 2; ++mi) {
                int row = wm * 32 + mi * 16 + l16;
                int off = ks * 32 + lq * 8;
                AF[mi] = *(const bf16x8*)&Tt[row * TS + off];
                AB[mi] = *(const bf16x8*)&Tf[row * TS + off];
            }
#pragma unroll
            for (int mi = 0; mi < 2; ++mi)
#pragma unroll
                for (int ni = 0; ni < 2; ++ni) {
                    tF[mi][ni] = __builtin_amdgcn_mfma_f32_16x16x32_bf16(
                        AF[mi], bfF[ni][ks], tF[mi][ni], 0, 0, 0);
                    tB[mi][ni] = __builtin_amdgcn_mfma_f32_16x16x32_bf16(
                        AB[mi], bfB[ni][ks], tB[mi][ni], 0, 0, 0);
                }
        }
        __syncthreads();

        // fold per-(w,r) chain weights (w = lane column)
#pragma unroll
        for (int ni = 0; ni < 2; ++ni) {
            int w = wn * 32 + ni * 16 + l16;
            float wfv = wfs[w * NREL + r];
            float wbv = wbs[w * NREL + r];
#pragma unroll
            for (int mi = 0; mi < 2; ++mi)
#pragma unroll
                for (int v = 0; v < 4; ++v) {
                    accF[mi][ni][v] += wfv * tF[mi][ni][v];
                    accB[mi][ni][v] += wbv * tB[mi][ni][v];
                }
        }
        g0 = n0v; g1 = n1v;
    }

    // bf16 partials, [node][w]-major
#pragma unroll
    for (int mi = 0; mi < 2; ++mi)
#pragma unroll
        for (int v = 0; v < 4; ++v) {
            int m = wm * 32 + mi * 16 + lq * 4 + v;
#pragma unroll
            for (int ni = 0; ni < 2; ++ni) {
                int w = wn * 32 + ni * 16 + l16;
                partF[(size_t)blockIdx.y * (NNODE * W128) + (B0 + m) * W128 + w]
                    = bf16t(accF[mi][ni][v]);
                partB[(size_t)blockIdx.x * (NNODE * W128) + (A0 + m) * W128 + w]
                    = bf16t(accB[mi][ni][v]);
            }
        }
}

// ---------------- reduce (+ per-thread opw softmax; replaces k_prep opw) ----
// grid (16 n-tiles x 8 w-tiles), 256 thr. Block tile: 64 n x 16 w.
__global__ __launch_bounds__(256) void k_reduce4(const float* __restrict__ ws,
                                                 const float* __restrict__ opww,
                                                 const short* __restrict__ partF,
                                                 const short* __restrict__ partB,
                                                 float* __restrict__ out) {
    __shared__ float chs[64 * 17];
    int t = threadIdx.x;
    int n0 = blockIdx.x * 64;
    int w0 = blockIdx.y * 16;
    // phase 1: reduce slices; thread owns (n_loc, 4 w's)
    {
        int n_loc = t >> 2;
        int wq = (t & 3) * 4;
        size_t base = (size_t)(n0 + n_loc) * W128 + w0 + wq;
        float c0 = 0.f, c1 = 0.f, c2 = 0.f, c3 = 0.f;
#pragma unroll
        for (int s = 0; s < 16; ++s) {
            short4v pf = *(const short4v*)&partF[(size_t)s * (NNODE * W128) + base];
            short4v pb = *(const short4v*)&partB[(size_t)s * (NNODE * W128) + base];
            c0 += bf16f(pf[0]) + bf16f(pb[0]);
            c1 += bf16f(pf[1]) + bf16f(pb[1]);
            c2 += bf16f(pf[2]) + bf16f(pb[2]);
            c3 += bf16f(pf[3]) + bf16f(pb[3]);
        }
        chs[n_loc * 17 + wq + 0] = c0;
        chs[n_loc * 17 + wq + 1] = c1;
        chs[n_loc * 17 + wq + 2] = c2;
        chs[n_loc * 17 + wq + 3] = c3;
    }
    __syncthreads();
    // phase 2: thread owns (w_loc, 4 n's); all global IO coalesced
    {
        int w_loc = t >> 4;          // 0..15
        int n4 = (t & 15) * 4;       // 0..60
        int w = w0 + w_loc;
        float ch[4];
#pragma unroll
        for (int j = 0; j < 4; ++j) ch[j] = chs[(n4 + j) * 17 + w_loc];
        // per-thread op-weight softmax (verified in fused phase 3)
        float v[5], mx = -1e30f;
#pragma unroll
        for (int k = 0; k < 5; ++k) { v[k] = opww[w * 5 + k]; mx = fmaxf(mx, v[k]); }
        float s5 = 0.f;
#pragma unroll
        for (int k = 0; k < 5; ++k) { v[k] = expf(v[k] - mx); s5 += v[k]; }
        float inv = 1.0f / s5;
        float4 a1 = *(const float4*)&ws[OFF_ARG1 + w * NNODE + n0 + n4];
        float4 a2 = *(const float4*)&ws[OFF_ARG2 + w * NNODE + n0 + n4];
        float a1v[4] = {a1.x, a1.y, a1.z, a1.w};
        float a2v[4] = {a2.x, a2.y, a2.z, a2.w};
        float ov[4];
#pragma unroll
        for (int j = 0; j < 4; ++j) {
            float p = a1v[j] * a2v[j];
            ov[j] = inv * (v[0] * a2v[j] + v[1] * p + v[2] * (a1v[j] + a2v[j] - p)
                  + v[3] * (1.0f - expf(-ch[j])) + v[4] * (1.0f - a1v[j]));
        }
        float4 o = {ov[0], ov[1], ov[2], ov[3]};
        *(float4*)&out[w * NNODE + n0 + n4] = o;
    }
}

extern "C" void kernel_launch(void* const* d_in, const int* in_sizes, int n_in,
                              void* d_out, int out_size, void* d_ws, size_t ws_size,
                              hipStream_t stream) {
    const float* inputs = (const float*)d_in[0];
    const float* db     = (const float*)d_in[1];
    const float* a1w    = (const float*)d_in[2];
    const float* a2w    = (const float*)d_in[3];
    const float* opww   = (const float*)d_in[4];
    const float* chw    = (const float*)d_in[5];
    float* ws  = (float*)d_ws;
    float* out = (float*)d_out;
    short* x2b   = (short*)(ws + OFF_ARG2B);
    short* partF = (short*)(ws + OFF_PART);
    short* partB = partF + (size_t)16 * NNODE * W128;

    hipLaunchKernelGGL(k_args3, dim3(256), dim3(512), 0, stream,
                       inputs, a1w, a2w, ws, x2b);
    hipLaunchKernelGGL(k_chain4, dim3(16, 16), dim3(512), 0, stream,
                       db, chw, x2b, partF, partB);
    hipLaunchKernelGGL(k_reduce4, dim3(16, 8), dim3(256), 0, stream,
                       ws, opww, partF, partB, out);
}